// Round 13
// baseline (581.768 us; speedup 1.0000x reference)
//
#include <hip/hip_runtime.h>

typedef float  f32x4 __attribute__((ext_vector_type(4)));
typedef short  s16x8 __attribute__((ext_vector_type(8)));

#define AS1 __attribute__((address_space(1)))
#define AS3 __attribute__((address_space(3)))

__device__ __forceinline__ void gload_lds16(const void* g, void* l) {
  __builtin_amdgcn_global_load_lds((AS1 void*)(g), (AS3 void*)(l), 16, 0, 0);
}

__device__ __forceinline__ void mfma_bf16(f32x4& d, s16x8 a, s16x8 b) {
  asm volatile("v_mfma_f32_16x16x32_bf16 %0, %1, %2, %0" : "+v"(d) : "v"(a), "v"(b));
}

// cached 16B loads in explicit issue order (opaque to compiler waitcnt insertion)
__device__ __forceinline__ void gload_b128(s16x8& d, const void* p) {
  asm volatile("global_load_dwordx4 %0, %1, off" : "=v"(d) : "v"(p));
}
__device__ __forceinline__ void gload_f128(f32x4& d, const void* p) {
  asm volatile("global_load_dwordx4 %0, %1, off" : "=v"(d) : "v"(p));
}

__device__ __forceinline__ unsigned short f2bf(float f) {
  union { float f; unsigned u; } v; v.f = f;
  unsigned u = v.u;
  unsigned r = u + 0x7fffu + ((u >> 16) & 1u);   // round-to-nearest-even
  return (unsigned short)(r >> 16);
}
__device__ __forceinline__ float bf2f(unsigned short u) {
  union { unsigned u; float f; } v; v.u = ((unsigned)u) << 16; return v.f;
}

// ---------------- fp32 -> bf16 convert ----------------
__launch_bounds__(256)
__global__ void cvt_bf16(const float* __restrict__ in, unsigned short* __restrict__ out, int n4) {
  for (int i = blockIdx.x * blockDim.x + threadIdx.x; i < n4; i += gridDim.x * blockDim.x) {
    float4 v = ((const float4*)in)[i];
    ushort4 u;
    u.x = f2bf(v.x); u.y = f2bf(v.y); u.z = f2bf(v.z); u.w = f2bf(v.w);
    ((ushort4*)out)[i] = u;
  }
}

// ---------------- h0 init: copy fp32 + bf16 ----------------
__launch_bounds__(256)
__global__ void init_h(const float* __restrict__ hid, float* __restrict__ hA,
                       unsigned short* __restrict__ hbf) {
  int i = blockIdx.x * 256 + threadIdx.x;
  float4 v = ((const float4*)hid)[i];
  ((float4*)hA)[i] = v;
  ushort4 u; u.x = f2bf(v.x); u.y = f2bf(v.y); u.z = f2bf(v.z); u.w = f2bf(v.w);
  ((ushort4*)hbf)[i] = u;
}

// ---------------- embedding gather + relu -> bf16 ----------------
__launch_bounds__(256)
__global__ void embed_relu(const int* __restrict__ tgt, const float* __restrict__ emb,
                           unsigned short* __restrict__ xbf) {
  int bid = blockIdx.x;
  int t = bid >> 6, b = bid & 63;
  int tok = (t == 0) ? 1 : tgt[(t - 1) * 64 + b];
  int c = threadIdx.x;
  float4 v = ((const float4*)(emb + (size_t)tok * 1024))[c];
  v.x = fmaxf(v.x, 0.f); v.y = fmaxf(v.y, 0.f); v.z = fmaxf(v.z, 0.f); v.w = fmaxf(v.w, 0.f);
  ushort4 u; u.x = f2bf(v.x); u.y = f2bf(v.y); u.z = f2bf(v.z); u.w = f2bf(v.w);
  ((ushort4*)(xbf + (size_t)bid * 1024))[c] = u;
}

// ---------------- standalone bf16 MFMA GEMM (used for the gi GEMM) ----------------
template<bool STATS, bool OUTBF>
__launch_bounds__(256)
__global__ void gemm_bt(const unsigned short* __restrict__ A,   // [M,K] bf16
                        const unsigned short* __restrict__ B,   // [N,K] bf16
                        const float* __restrict__ bias,         // [N] fp32
                        float* __restrict__ Cf,                 // [M,N] fp32 (if !OUTBF)
                        unsigned short* __restrict__ Cb,        // [M,N] bf16 (if OUTBF)
                        float2* __restrict__ stats,             // [M, nTilesTotal]
                        int N, int K, int mTiles, int nTilesTotal) {
  __shared__ unsigned short As[128 * 64];
  __shared__ unsigned short Bs[128 * 64];
  __shared__ float2 sstat[2][128];

  const int tid = threadIdx.x;
  int bid = blockIdx.x;
  { // XCD swizzle (gridDim.x % 8 == 0)
    int q = gridDim.x >> 3;
    bid = (bid & 7) * q + (bid >> 3);
  }
  const int tileN = bid / mTiles;
  const int tileM = bid % mTiles;
  const int m0 = tileM * 128, n0 = tileN * 128;
  const int lane = tid & 63;
  const int w = tid >> 6, wr = w >> 1, wc = w & 1;
  const int lr = lane & 15, lg = lane >> 4;

  f32x4 acc[4][4];
#pragma unroll
  for (int m = 0; m < 4; ++m)
#pragma unroll
    for (int n = 0; n < 4; ++n) acc[m][n] = (f32x4){0.f, 0.f, 0.f, 0.f};

  const int crow = tid >> 3;
  const int cj   = tid & 7;

  for (int kt = 0; kt < K; kt += 64) {
#pragma unroll
    for (int it = 0; it < 4; ++it) {
      int row = it * 32 + crow;
      int sb = ((cj * 16) ^ ((row & 7) << 4)) >> 1;
      gload_lds16(A + (size_t)(m0 + row) * K + kt + sb, &As[row * 64 + cj * 8]);
      gload_lds16(B + (size_t)(n0 + row) * K + kt + sb, &Bs[row * 64 + cj * 8]);
    }
    __syncthreads();
#pragma unroll
    for (int kk = 0; kk < 2; ++kk) {
      s16x8 af[4], bfr[4];
#pragma unroll
      for (int m = 0; m < 4; ++m) {
        int row = wr * 64 + m * 16 + lr;
        int off = ((kk * 64 + lg * 16) ^ ((row & 7) << 4)) >> 1;
        af[m] = *reinterpret_cast<const s16x8*>(&As[row * 64 + off]);
      }
#pragma unroll
      for (int n = 0; n < 4; ++n) {
        int row = wc * 64 + n * 16 + lr;
        int off = ((kk * 64 + lg * 16) ^ ((row & 7) << 4)) >> 1;
        bfr[n] = *reinterpret_cast<const s16x8*>(&Bs[row * 64 + off]);
      }
#pragma unroll
      for (int m = 0; m < 4; ++m)
#pragma unroll
        for (int n = 0; n < 4; ++n) mfma_bf16(acc[m][n], af[m], bfr[n]);
    }
    __syncthreads();
  }

  float bv[4];
#pragma unroll
  for (int n = 0; n < 4; ++n) bv[n] = bias[n0 + wc * 64 + n * 16 + lr];
#pragma unroll
  for (int m = 0; m < 4; ++m)
#pragma unroll
    for (int n = 0; n < 4; ++n)
#pragma unroll
      for (int j = 0; j < 4; ++j) acc[m][n][j] += bv[n];

#pragma unroll
  for (int m = 0; m < 4; ++m) {
    int rbase = m0 + wr * 64 + m * 16 + lg * 4;
#pragma unroll
    for (int j = 0; j < 4; ++j) {
      size_t roff = (size_t)(rbase + j) * N;
#pragma unroll
      for (int n = 0; n < 4; ++n) {
        size_t idx = roff + n0 + wc * 64 + n * 16 + lr;
        if (OUTBF) Cb[idx] = f2bf(acc[m][n][j]);
        else       Cf[idx] = acc[m][n][j];
      }
    }
  }

  if (STATS) {
#pragma unroll
    for (int m = 0; m < 4; ++m) {
#pragma unroll
      for (int j = 0; j < 4; ++j) {
        float vmax = acc[m][0][j];
#pragma unroll
        for (int n = 1; n < 4; ++n) vmax = fmaxf(vmax, acc[m][n][j]);
#pragma unroll
        for (int s = 1; s < 16; s <<= 1) vmax = fmaxf(vmax, __shfl_xor(vmax, s, 64));
        float ss = 0.f;
#pragma unroll
        for (int n = 0; n < 4; ++n) ss += __expf(acc[m][n][j] - vmax);
#pragma unroll
        for (int s = 1; s < 16; s <<= 1) ss += __shfl_xor(ss, s, 64);
        if (lr == 0) sstat[wc][wr * 64 + m * 16 + lg * 4 + j] = make_float2(vmax, ss);
      }
    }
    __syncthreads();
    if (tid < 128) {
      float2 a = sstat[0][tid], b = sstat[1][tid];
      float Mx = fmaxf(a.x, b.x);
      float S = a.y * __expf(a.x - Mx) + b.y * __expf(b.x - Mx);
      stats[(size_t)(m0 + tid) * nTilesTotal + tileN] = make_float2(Mx, S);
    }
  }
}

// ======================= fused scan + logits GEMM =======================
// 240 blocks x 256 threads, 1 block/CU (96KB LDS) -> ALL co-resident by capacity
// (240 <= 256, so no deadlock regardless of dispatch order).
// Blocks 0..63: v7 GRU scan producers (flag-barrier now publishes after step 31 too).
// Blocks 64..239: logits-GEMM consumers. M-tile mt (128 rows = timesteps 2mt,2mt+1)
// is ready when all 64 flags >= 2mt+2; consumers round-robin the 4000 tiles in
// mt-major order, poll flags (relaxed agent loads probe MALL), then run a 128x128
// tile with 2-phase double-buffered staging (T3-minimum: STAGE(k+1,buf^1) ->
// compute(k,buf) -> syncthreads) to compensate the 1-block/CU occupancy.
// Coherence: launch-acquire invalidate + each outs_bf line written exactly once
// (write-through atomic) + read only after flag => cached reads are always fresh.
template<bool OUTBF>
__launch_bounds__(256, 1)
__global__ void scan_fused(const unsigned short* __restrict__ whh,  // [3072,1024] bf16
                           const float* __restrict__ gi,            // [32*64,3072] fp32
                           const float* __restrict__ bhh,           // [3072]
                           float* __restrict__ h,                   // [64,1024] fp32
                           unsigned short* __restrict__ outs_bf,    // [(L+1)*64*1024]
                           unsigned* __restrict__ bar,              // 64 flags, 128B apart
                           const unsigned short* __restrict__ fcw,  // [32000,1024] bf16
                           const float* __restrict__ fcb,           // [32000]
                           float* __restrict__ Cf,                  // logits fp32 (if !OUTBF)
                           unsigned short* __restrict__ Cb,         // logits bf16 (if OUTBF)
                           float2* __restrict__ stats) {            // [2048,250]
  __shared__ char smem[96 * 1024];
  const int tid = threadIdx.x, lane = tid & 63, w = tid >> 6;
  const int lr = lane & 15, lg = lane >> 4;
  const int bid = blockIdx.x;

  if (bid < 64) {
    // ========================= producer: GRU scan (v7) =========================
    char* lds = smem;
    const int j0 = bid * 16;

    for (int c = tid; c < 6144; c += 256) {
      int chunk = c >> 6, u = c & 63;
      int g = chunk >> 5, K = chunk & 31;
      gload_lds16(whh + (size_t)(g * 1024 + j0 + (u & 15)) * 1024 + K * 32 + (u >> 4) * 8,
                  lds + (size_t)c * 16);
    }

    const int b  = w * 16 + lr;
    const int c0 = j0 + lg * 4;

    float4 bhr = *(const float4*)(bhh + c0);
    float4 bhz = *(const float4*)(bhh + 1024 + c0);
    float4 bhn = *(const float4*)(bhh + 2048 + c0);

    float4 hv = *(const float4*)(h + (size_t)b * 1024 + c0);
    f32x4 cr, cz, cn;
    {
      const float* g0 = gi + (size_t)b * 3072 + c0;
      cr = *(const f32x4*)(g0);
      cz = *(const f32x4*)(g0 + 1024);
      cn = *(const f32x4*)(g0 + 2048);
    }

    __syncthreads();

#define WAITV(n)                                               \
  asm volatile("s_waitcnt vmcnt(" #n ")" ::: "memory");        \
  __builtin_amdgcn_sched_barrier(0);
#define ISSUE8(q, ibase)                                       \
  _Pragma("unroll")                                            \
  for (int j = 0; j < 8; ++j)                                  \
    gload_b128(q[j], rowp + ((ibase) + j) * 4 + lg);
#define MFMA8(q, ibase)                                        \
  _Pragma("unroll")                                            \
  for (int j = 0; j < 8; ++j) {                                \
    _Pragma("unroll")                                          \
    for (int g = 0; g < 3; ++g) {                              \
      s16x8 wf = *reinterpret_cast<const s16x8*>(              \
          lds + (size_t)(g * 32 + (ibase) + j) * 1024 + lane * 16); \
      mfma_bf16(acc[g], wf, q[j]);                             \
    }                                                          \
  }

    for (int t = 0; t < 32; ++t) {
      const s16x8* rowp = (const s16x8*)(outs_bf + (size_t)t * 65536 + (size_t)b * 1024);

      f32x4 nr, nz, nn;
      {
        int tn = (t < 31) ? t + 1 : 31;
        const float* gn = gi + ((size_t)tn * 64 + b) * 3072 + c0;
        gload_f128(nr, gn);
        gload_f128(nz, gn + 1024);
        gload_f128(nn, gn + 2048);
      }
      s16x8 qa[8], qb[8];
      ISSUE8(qa, 0)
      ISSUE8(qb, 8)

      f32x4 acc[3];
#pragma unroll
      for (int g = 0; g < 3; ++g) acc[g] = (f32x4){0.f, 0.f, 0.f, 0.f};

      WAITV(8)
      MFMA8(qa, 0)
      ISSUE8(qa, 16)
      WAITV(8)
      MFMA8(qb, 8)
      ISSUE8(qb, 24)
      WAITV(8)
      MFMA8(qa, 16)
      WAITV(0)
      MFMA8(qb, 24)

      float hvv[4] = {hv.x, hv.y, hv.z, hv.w};
      float crr[4] = {cr[0], cr[1], cr[2], cr[3]}, czz[4] = {cz[0], cz[1], cz[2], cz[3]},
            cnn[4] = {cn[0], cn[1], cn[2], cn[3]};
      float brr[4] = {bhr.x, bhr.y, bhr.z, bhr.w}, bzz[4] = {bhz.x, bhz.y, bhz.z, bhz.w},
            bnn[4] = {bhn.x, bhn.y, bhn.z, bhn.w};
      unsigned long long pk = 0;
#pragma unroll
      for (int j = 0; j < 4; ++j) {
        float r = 1.f / (1.f + __expf(-(crr[j] + acc[0][j] + brr[j])));
        float z = 1.f / (1.f + __expf(-(czz[j] + acc[1][j] + bzz[j])));
        float n = tanhf(cnn[j] + r * (acc[2][j] + bnn[j]));
        hvv[j] = n + z * (hvv[j] - n);
        pk |= (unsigned long long)f2bf(hvv[j]) << (16 * j);
      }
      hv = (float4){hvv[0], hvv[1], hvv[2], hvv[3]};
      cr = nr; cz = nz; cn = nn;

      __hip_atomic_store(
          (unsigned long long*)(outs_bf + (size_t)(t + 1) * 65536 + (size_t)b * 1024 + c0),
          pk, __ATOMIC_RELAXED, __HIP_MEMORY_SCOPE_AGENT);

      // barrier + flag publish (publish ALL steps incl. t=31 for consumers)
      asm volatile("s_waitcnt vmcnt(0)" ::: "memory");  // h stores acked at MALL
      __syncthreads();
      if (tid == 0)
        __hip_atomic_store(&bar[bid * 32], (unsigned)(t + 1),
                           __ATOMIC_RELAXED, __HIP_MEMORY_SCOPE_AGENT);
      if (t < 31) {
        if (tid < 64) {
          while (__hip_atomic_load(&bar[tid * 32], __ATOMIC_RELAXED,
                                   __HIP_MEMORY_SCOPE_AGENT) < (unsigned)(t + 1))
            __builtin_amdgcn_s_sleep(1);
        }
        __syncthreads();
      }
    }
#undef WAITV
#undef ISSUE8
#undef MFMA8

    *(float4*)(h + (size_t)b * 1024 + c0) = hv;

  } else {
    // ========================= consumer: logits GEMM =========================
    unsigned short* As0 = (unsigned short*)smem;
    unsigned short* Bs0 = (unsigned short*)(smem + 16384);
    unsigned short* As1 = (unsigned short*)(smem + 32768);
    unsigned short* Bs1 = (unsigned short*)(smem + 49152);
    float2* sstat = (float2*)(smem + 65536);   // [2][128]

    const unsigned short* Ag = outs_bf + 65536;   // slot 1 = timestep 0 (rows t*64+b)
    const unsigned short* Bg = fcw;
    const int cb = bid - 64;
    const int wr = w >> 1, wc = w & 1;
    const int crow = tid >> 3, cj = tid & 7;

#define CSTAGE(Asp, Bsp, kt)                                                        \
    _Pragma("unroll")                                                               \
    for (int it = 0; it < 4; ++it) {                                                \
      int row = it * 32 + crow;                                                     \
      int sb = ((cj * 16) ^ ((row & 7) << 4)) >> 1;                                 \
      gload_lds16(Ag + (size_t)(m0 + row) * 1024 + (kt) + sb, Asp + row * 64 + cj * 8); \
      gload_lds16(Bg + (size_t)(n0 + row) * 1024 + (kt) + sb, Bsp + row * 64 + cj * 8); \
    }
#define CCOMP(Asp, Bsp)                                                             \
    _Pragma("unroll")                                                               \
    for (int kk = 0; kk < 2; ++kk) {                                                \
      s16x8 af[4], bfr[4];                                                          \
      _Pragma("unroll")                                                             \
      for (int m = 0; m < 4; ++m) {                                                 \
        int row = wr * 64 + m * 16 + lr;                                            \
        int off = ((kk * 64 + lg * 16) ^ ((row & 7) << 4)) >> 1;                    \
        af[m] = *reinterpret_cast<const s16x8*>(&Asp[row * 64 + off]);              \
      }                                                                             \
      _Pragma("unroll")                                                             \
      for (int n = 0; n < 4; ++n) {                                                 \
        int row = wc * 64 + n * 16 + lr;                                            \
        int off = ((kk * 64 + lg * 16) ^ ((row & 7) << 4)) >> 1;                    \
        bfr[n] = *reinterpret_cast<const s16x8*>(&Bsp[row * 64 + off]);             \
      }                                                                             \
      _Pragma("unroll")                                                             \
      for (int m = 0; m < 4; ++m)                                                   \
        _Pragma("unroll")                                                           \
        for (int n = 0; n < 4; ++n) mfma_bf16(acc[m][n], af[m], bfr[n]);            \
    }

    for (int tau = cb; tau < 4000; tau += 176) {
      int mt = tau / 250, nt = tau - mt * 250;
      int m0 = mt * 128, n0 = nt * 128;

      // wait until timesteps 2mt, 2mt+1 are published by all 64 producers
      unsigned need = 2u * (unsigned)mt + 2u;
      while (!__all(__hip_atomic_load(&bar[lane * 32], __ATOMIC_RELAXED,
                                      __HIP_MEMORY_SCOPE_AGENT) >= need))
        __builtin_amdgcn_s_sleep(2);

      f32x4 acc[4][4];
#pragma unroll
      for (int m = 0; m < 4; ++m)
#pragma unroll
        for (int n = 0; n < 4; ++n) acc[m][n] = (f32x4){0.f, 0.f, 0.f, 0.f};

      // 2-phase double-buffered K loop: stage(k+1) flies under compute(k)
      CSTAGE(As0, Bs0, 0)
      __syncthreads();
#pragma unroll 2
      for (int ki = 0; ki < 16; ++ki) {
        if (ki & 1) {
          if (ki < 15) CSTAGE(As0, Bs0, (ki + 1) * 64)
          CCOMP(As1, Bs1)
        } else {
          if (ki < 15) CSTAGE(As1, Bs1, (ki + 1) * 64)
          CCOMP(As0, Bs0)
        }
        __syncthreads();   // drains vmcnt (stage k+1 landed) + all waves done with buf
      }

      float bv[4];
#pragma unroll
      for (int n = 0; n < 4; ++n) bv[n] = fcb[n0 + wc * 64 + n * 16 + lr];
#pragma unroll
      for (int m = 0; m < 4; ++m)
#pragma unroll
        for (int n = 0; n < 4; ++n)
#pragma unroll
          for (int j = 0; j < 4; ++j) acc[m][n][j] += bv[n];

#pragma unroll
      for (int m = 0; m < 4; ++m) {
        int rbase = m0 + wr * 64 + m * 16 + lg * 4;
#pragma unroll
        for (int j = 0; j < 4; ++j) {
          size_t roff = (size_t)(rbase + j) * 32000;
#pragma unroll
          for (int n = 0; n < 4; ++n) {
            size_t idx = roff + n0 + wc * 64 + n * 16 + lr;
            if (OUTBF) Cb[idx] = f2bf(acc[m][n][j]);
            else       Cf[idx] = acc[m][n][j];
          }
        }
      }

      // per-tile softmax partials
#pragma unroll
      for (int m = 0; m < 4; ++m) {
#pragma unroll
        for (int j = 0; j < 4; ++j) {
          float vmax = acc[m][0][j];
#pragma unroll
          for (int n = 1; n < 4; ++n) vmax = fmaxf(vmax, acc[m][n][j]);
#pragma unroll
          for (int s = 1; s < 16; s <<= 1) vmax = fmaxf(vmax, __shfl_xor(vmax, s, 64));
          float ss = 0.f;
#pragma unroll
          for (int n = 0; n < 4; ++n) ss += __expf(acc[m][n][j] - vmax);
#pragma unroll
          for (int s = 1; s < 16; s <<= 1) ss += __shfl_xor(ss, s, 64);
          if (lr == 0) sstat[wc * 128 + wr * 64 + m * 16 + lg * 4 + j] = make_float2(vmax, ss);
        }
      }
      __syncthreads();
      if (tid < 128) {
        float2 a = sstat[tid], b2 = sstat[128 + tid];
        float Mx = fmaxf(a.x, b2.x);
        float S = a.y * __expf(a.x - Mx) + b2.y * __expf(b2.x - Mx);
        stats[(size_t)(m0 + tid) * 250 + nt] = make_float2(Mx, S);
      }
      __syncthreads();   // sstat reads done before next tile's staging
    }
#undef CSTAGE
#undef CCOMP
  }
}

// ---------------- per-row logZ from tile partials ----------------
__launch_bounds__(256)
__global__ void reduce_logz(const float2* __restrict__ stats, float* __restrict__ logZ, int nt) {
  int gid = blockIdx.x * blockDim.x + threadIdx.x;
  int row = gid >> 6, lane = gid & 63;
  const float2* s = stats + (size_t)row * nt;
  float M = -3.4e38f;
  for (int i = lane; i < nt; i += 64) M = fmaxf(M, s[i].x);
#pragma unroll
  for (int sh = 1; sh < 64; sh <<= 1) M = fmaxf(M, __shfl_xor(M, sh, 64));
  float S = 0.f;
  for (int i = lane; i < nt; i += 64) S += s[i].y * __expf(s[i].x - M);
#pragma unroll
  for (int sh = 1; sh < 64; sh <<= 1) S += __shfl_xor(S, sh, 64);
  if (lane == 0) logZ[row] = M + logf(S);
}

// ---------------- fixup (fast path): bf16 logits -> fp32 log_probs ----------------
__launch_bounds__(256)
__global__ void fixup_bf(const unsigned short* __restrict__ lbf, const float* __restrict__ logZ,
                         float* __restrict__ out) {
  const int n8 = 2048 * 32000 / 8;
  for (int i = blockIdx.x * 256 + threadIdx.x; i < n8; i += gridDim.x * 256) {
    s16x8 v = reinterpret_cast<const s16x8*>(lbf)[i];
    float z = logZ[i / 4000];
    float4 o0, o1;
    o0.x = bf2f((unsigned short)v[0]) - z; o0.y = bf2f((unsigned short)v[1]) - z;
    o0.z = bf2f((unsigned short)v[2]) - z; o0.w = bf2f((unsigned short)v[3]) - z;
    o1.x = bf2f((unsigned short)v[4]) - z; o1.y = bf2f((unsigned short)v[5]) - z;
    o1.z = bf2f((unsigned short)v[6]) - z; o1.w = bf2f((unsigned short)v[7]) - z;
    reinterpret_cast<float4*>(out)[2 * i]     = o0;
    reinterpret_cast<float4*>(out)[2 * i + 1] = o1;
  }
}

// ---------------- fixup (fallback): in-place RMW on fp32 logits ----------------
__launch_bounds__(256)
__global__ void fixup_rmw(float* __restrict__ out, const float* __restrict__ logZ) {
  const size_t total4 = 65536000u / 4u;
  for (size_t i = blockIdx.x * (size_t)blockDim.x + threadIdx.x; i < total4;
       i += (size_t)gridDim.x * blockDim.x) {
    float4 v = ((float4*)out)[i];
    int row = (int)((i * 4) / 32000);
    float z = logZ[row];
    v.x -= z; v.y -= z; v.z -= z; v.w -= z;
    ((float4*)out)[i] = v;
  }
}

// ---------------- h_last copy ----------------
__launch_bounds__(256)
__global__ void copy_h(const float* __restrict__ src, float* __restrict__ dst) {
  int i = blockIdx.x * 256 + threadIdx.x;
  ((float4*)dst)[i] = ((const float4*)src)[i];
}

extern "C" void kernel_launch(void* const* d_in, const int* in_sizes, int n_in,
                              void* d_out, int out_size, void* d_ws, size_t ws_size,
                              hipStream_t stream) {
  const int*   target = (const int*)d_in[0];
  const float* hidden = (const float*)d_in[2];
  const float* emb    = (const float*)d_in[3];
  const float* wih    = (const float*)d_in[4];
  const float* whh    = (const float*)d_in[5];
  const float* bih    = (const float*)d_in[6];
  const float* bhh    = (const float*)d_in[7];
  const float* fcw    = (const float*)d_in[8];
  const float* fcb    = (const float*)d_in[9];
  float* out = (float*)d_out;

  const int L = 32, B = 64, H = 1024, V = 32000;
  const int LB = L * B;                 // 2048
  const int NT_LOGITS = V / 128;        // 250
  const int MT = LB / 128;              // 16

  char* ws = (char*)d_ws;
  size_t off = 0;
  auto alloc = [&](size_t bytes) -> void* {
    void* p = ws + off;
    off += (bytes + 255) & ~(size_t)255;
    return p;
  };
  unsigned short* wih_bf  = (unsigned short*)alloc((size_t)3 * H * H * 2);
  unsigned short* whh_bf  = (unsigned short*)alloc((size_t)3 * H * H * 2);
  unsigned short* fcw_bf  = (unsigned short*)alloc((size_t)V * H * 2);
  unsigned short* x_bf    = (unsigned short*)alloc((size_t)LB * H * 2);
  unsigned short* outs_bf = (unsigned short*)alloc((size_t)(L + 1) * B * H * 2);
  float*          gi      = (float*)alloc((size_t)LB * 3 * H * 4);
  float*          hA      = (float*)alloc((size_t)B * H * 4);
  float2*         stats   = (float2*)alloc((size_t)LB * NT_LOGITS * 8);
  float*          logZ    = (float*)alloc((size_t)LB * 4);
  unsigned*       bar     = (unsigned*)alloc(64 * 128);   // 64 flags, 128B apart
  size_t lbf_bytes = (size_t)LB * V * 2;
  unsigned short* lbf = (unsigned short*)(ws + off);
  bool big = (off + lbf_bytes) <= ws_size;
  (void)in_sizes; (void)n_in; (void)out_size;

  // weights -> bf16
  cvt_bf16<<<2048, 256, 0, stream>>>(wih, wih_bf, 3 * H * H / 4);
  cvt_bf16<<<2048, 256, 0, stream>>>(whh, whh_bf, 3 * H * H / 4);
  cvt_bf16<<<2048, 256, 0, stream>>>(fcw, fcw_bf, V * H / 4);

  // h0
  init_h<<<64, 256, 0, stream>>>(hidden, hA, outs_bf);

  // x = relu(emb[tokens]) -> bf16
  embed_relu<<<LB, 256, 0, stream>>>(target, emb, x_bf);

  // gi = x @ w_ih^T + b_ih   (M=2048, N=3072, K=1024)
  gemm_bt<false, false><<<(3 * H / 128) * MT, 256, 0, stream>>>(
      x_bf, wih_bf, bih, gi, nullptr, nullptr, 3 * H, H, MT, 3 * H / 128);

  // fused persistent scan + logits GEMM (flags zeroed each call -> deterministic)
  hipMemsetAsync(bar, 0, 64 * 128, stream);
  if (big) {
    scan_fused<true><<<240, 256, 0, stream>>>(
        whh_bf, gi, bhh, hA, outs_bf, bar, fcw_bf, fcb, nullptr, lbf, stats);
    reduce_logz<<<LB * 64 / 256, 256, 0, stream>>>(stats, logZ, NT_LOGITS);
    fixup_bf<<<2048, 256, 0, stream>>>(lbf, logZ, out);
  } else {
    scan_fused<false><<<240, 256, 0, stream>>>(
        whh_bf, gi, bhh, hA, outs_bf, bar, fcw_bf, fcb, out, nullptr, stats);
    reduce_logz<<<LB * 64 / 256, 256, 0, stream>>>(stats, logZ, NT_LOGITS);
    fixup_rmw<<<2048, 256, 0, stream>>>(out, logZ);
  }

  // h_last
  copy_h<<<64, 256, 0, stream>>>(hA, out + (size_t)LB * V);
}

// Round 14
// 552.472 us; speedup vs baseline: 1.0530x; 1.0530x over previous
//
#include <hip/hip_runtime.h>

typedef float  f32x4 __attribute__((ext_vector_type(4)));
typedef short  s16x8 __attribute__((ext_vector_type(8)));

#define AS1 __attribute__((address_space(1)))
#define AS3 __attribute__((address_space(3)))

__device__ __forceinline__ void gload_lds16(const void* g, void* l) {
  __builtin_amdgcn_global_load_lds((AS1 void*)(g), (AS3 void*)(l), 16, 0, 0);
}

__device__ __forceinline__ void mfma_bf16(f32x4& d, s16x8 a, s16x8 b) {
  asm volatile("v_mfma_f32_16x16x32_bf16 %0, %1, %2, %0" : "+v"(d) : "v"(a), "v"(b));
}

// cached 16B loads in explicit issue order (opaque to compiler waitcnt insertion)
__device__ __forceinline__ void gload_b128(s16x8& d, const void* p) {
  asm volatile("global_load_dwordx4 %0, %1, off" : "=v"(d) : "v"(p));
}
__device__ __forceinline__ void gload_f128(f32x4& d, const void* p) {
  asm volatile("global_load_dwordx4 %0, %1, off" : "=v"(d) : "v"(p));
}

__device__ __forceinline__ unsigned short f2bf(float f) {
  union { float f; unsigned u; } v; v.f = f;
  unsigned u = v.u;
  unsigned r = u + 0x7fffu + ((u >> 16) & 1u);   // round-to-nearest-even
  return (unsigned short)(r >> 16);
}
__device__ __forceinline__ float bf2f(unsigned short u) {
  union { unsigned u; float f; } v; v.u = ((unsigned)u) << 16; return v.f;
}

// ---------------- fp32 -> bf16 convert ----------------
__launch_bounds__(256)
__global__ void cvt_bf16(const float* __restrict__ in, unsigned short* __restrict__ out, int n4) {
  for (int i = blockIdx.x * blockDim.x + threadIdx.x; i < n4; i += gridDim.x * blockDim.x) {
    float4 v = ((const float4*)in)[i];
    ushort4 u;
    u.x = f2bf(v.x); u.y = f2bf(v.y); u.z = f2bf(v.z); u.w = f2bf(v.w);
    ((ushort4*)out)[i] = u;
  }
}

// ---------------- h0 init: copy fp32 + bf16 ----------------
__launch_bounds__(256)
__global__ void init_h(const float* __restrict__ hid, float* __restrict__ hA,
                       unsigned short* __restrict__ hbf) {
  int i = blockIdx.x * 256 + threadIdx.x;
  float4 v = ((const float4*)hid)[i];
  ((float4*)hA)[i] = v;
  ushort4 u; u.x = f2bf(v.x); u.y = f2bf(v.y); u.z = f2bf(v.z); u.w = f2bf(v.w);
  ((ushort4*)hbf)[i] = u;
}

// ---------------- embedding gather + relu -> bf16 ----------------
__launch_bounds__(256)
__global__ void embed_relu(const int* __restrict__ tgt, const float* __restrict__ emb,
                           unsigned short* __restrict__ xbf) {
  int bid = blockIdx.x;
  int t = bid >> 6, b = bid & 63;
  int tok = (t == 0) ? 1 : tgt[(t - 1) * 64 + b];
  int c = threadIdx.x;
  float4 v = ((const float4*)(emb + (size_t)tok * 1024))[c];
  v.x = fmaxf(v.x, 0.f); v.y = fmaxf(v.y, 0.f); v.z = fmaxf(v.z, 0.f); v.w = fmaxf(v.w, 0.f);
  ushort4 u; u.x = f2bf(v.x); u.y = f2bf(v.y); u.z = f2bf(v.z); u.w = f2bf(v.w);
  ((ushort4*)(xbf + (size_t)bid * 1024))[c] = u;
}

// ---------------- standalone bf16 MFMA GEMM (used for the gi GEMM) ----------------
template<bool STATS, bool OUTBF>
__launch_bounds__(256)
__global__ void gemm_bt(const unsigned short* __restrict__ A,   // [M,K] bf16
                        const unsigned short* __restrict__ B,   // [N,K] bf16
                        const float* __restrict__ bias,         // [N] fp32
                        float* __restrict__ Cf,                 // [M,N] fp32 (if !OUTBF)
                        unsigned short* __restrict__ Cb,        // [M,N] bf16 (if OUTBF)
                        float2* __restrict__ stats,             // [M, nTilesTotal]
                        int N, int K, int mTiles, int nTilesTotal) {
  __shared__ unsigned short As[128 * 64];
  __shared__ unsigned short Bs[128 * 64];
  __shared__ float2 sstat[2][128];

  const int tid = threadIdx.x;
  int bid = blockIdx.x;
  { // XCD swizzle (gridDim.x % 8 == 0)
    int q = gridDim.x >> 3;
    bid = (bid & 7) * q + (bid >> 3);
  }
  const int tileN = bid / mTiles;
  const int tileM = bid % mTiles;
  const int m0 = tileM * 128, n0 = tileN * 128;
  const int lane = tid & 63;
  const int w = tid >> 6, wr = w >> 1, wc = w & 1;
  const int lr = lane & 15, lg = lane >> 4;

  f32x4 acc[4][4];
#pragma unroll
  for (int m = 0; m < 4; ++m)
#pragma unroll
    for (int n = 0; n < 4; ++n) acc[m][n] = (f32x4){0.f, 0.f, 0.f, 0.f};

  const int crow = tid >> 3;
  const int cj   = tid & 7;

  for (int kt = 0; kt < K; kt += 64) {
#pragma unroll
    for (int it = 0; it < 4; ++it) {
      int row = it * 32 + crow;
      int sb = ((cj * 16) ^ ((row & 7) << 4)) >> 1;
      gload_lds16(A + (size_t)(m0 + row) * K + kt + sb, &As[row * 64 + cj * 8]);
      gload_lds16(B + (size_t)(n0 + row) * K + kt + sb, &Bs[row * 64 + cj * 8]);
    }
    __syncthreads();
#pragma unroll
    for (int kk = 0; kk < 2; ++kk) {
      s16x8 af[4], bfr[4];
#pragma unroll
      for (int m = 0; m < 4; ++m) {
        int row = wr * 64 + m * 16 + lr;
        int off = ((kk * 64 + lg * 16) ^ ((row & 7) << 4)) >> 1;
        af[m] = *reinterpret_cast<const s16x8*>(&As[row * 64 + off]);
      }
#pragma unroll
      for (int n = 0; n < 4; ++n) {
        int row = wc * 64 + n * 16 + lr;
        int off = ((kk * 64 + lg * 16) ^ ((row & 7) << 4)) >> 1;
        bfr[n] = *reinterpret_cast<const s16x8*>(&Bs[row * 64 + off]);
      }
#pragma unroll
      for (int m = 0; m < 4; ++m)
#pragma unroll
        for (int n = 0; n < 4; ++n) mfma_bf16(acc[m][n], af[m], bfr[n]);
    }
    __syncthreads();
  }

  float bv[4];
#pragma unroll
  for (int n = 0; n < 4; ++n) bv[n] = bias[n0 + wc * 64 + n * 16 + lr];
#pragma unroll
  for (int m = 0; m < 4; ++m)
#pragma unroll
    for (int n = 0; n < 4; ++n)
#pragma unroll
      for (int j = 0; j < 4; ++j) acc[m][n][j] += bv[n];

#pragma unroll
  for (int m = 0; m < 4; ++m) {
    int rbase = m0 + wr * 64 + m * 16 + lg * 4;
#pragma unroll
    for (int j = 0; j < 4; ++j) {
      size_t roff = (size_t)(rbase + j) * N;
#pragma unroll
      for (int n = 0; n < 4; ++n) {
        size_t idx = roff + n0 + wc * 64 + n * 16 + lr;
        if (OUTBF) Cb[idx] = f2bf(acc[m][n][j]);
        else       Cf[idx] = acc[m][n][j];
      }
    }
  }

  if (STATS) {
#pragma unroll
    for (int m = 0; m < 4; ++m) {
#pragma unroll
      for (int j = 0; j < 4; ++j) {
        float vmax = acc[m][0][j];
#pragma unroll
        for (int n = 1; n < 4; ++n) vmax = fmaxf(vmax, acc[m][n][j]);
#pragma unroll
        for (int s = 1; s < 16; s <<= 1) vmax = fmaxf(vmax, __shfl_xor(vmax, s, 64));
        float ss = 0.f;
#pragma unroll
        for (int n = 0; n < 4; ++n) ss += __expf(acc[m][n][j] - vmax);
#pragma unroll
        for (int s = 1; s < 16; s <<= 1) ss += __shfl_xor(ss, s, 64);
        if (lr == 0) sstat[wc][wr * 64 + m * 16 + lg * 4 + j] = make_float2(vmax, ss);
      }
    }
    __syncthreads();
    if (tid < 128) {
      float2 a = sstat[0][tid], b = sstat[1][tid];
      float Mx = fmaxf(a.x, b.x);
      float S = a.y * __expf(a.x - Mx) + b.y * __expf(b.x - Mx);
      stats[(size_t)(m0 + tid) * nTilesTotal + tileN] = make_float2(Mx, S);
    }
  }
}

// ======================= fused scan + logits GEMM v2 =======================
// 240 blocks x 256 threads, 1 block/CU (96KB LDS) -> all co-resident by capacity.
// Blocks 0..63: v7 GRU scan producers (unchanged). Blocks 64..239: consumers.
// Consumer v2 (R13 was consumer-throughput-bound at 19.3us/tile, drain-to-0 stall):
//   * 3 LDS buffers (3x32KB), stage TWO K-steps ahead
//   * counted s_waitcnt vmcnt(16) (T4) — never drains to 0 in the main loop;
//     raw s_barrier (no implicit vmcnt(0), unlike __syncthreads)
//   * stage(ki) gets ~2 iterations of flight time -> latency fully hidden
//   * sstat aliases buf0 after the K-loop (LDS stays 96KB)
//   * only wave 0 polls readiness flags, s_sleep(32) between probes (keeps
//     consumer probe traffic off the scan's MALL path)
// Epilogue __syncthreads() drains vmcnt to 0, so per-tile counted waits stay exact.
template<bool OUTBF>
__launch_bounds__(256, 1)
__global__ void scan_fused(const unsigned short* __restrict__ whh,  // [3072,1024] bf16
                           const float* __restrict__ gi,            // [32*64,3072] fp32
                           const float* __restrict__ bhh,           // [3072]
                           float* __restrict__ h,                   // [64,1024] fp32
                           unsigned short* __restrict__ outs_bf,    // [(L+1)*64*1024]
                           unsigned* __restrict__ bar,              // 64 flags, 128B apart
                           const unsigned short* __restrict__ fcw,  // [32000,1024] bf16
                           const float* __restrict__ fcb,           // [32000]
                           float* __restrict__ Cf,                  // logits fp32 (if !OUTBF)
                           unsigned short* __restrict__ Cb,         // logits bf16 (if OUTBF)
                           float2* __restrict__ stats) {            // [2048,250]
  __shared__ char smem[96 * 1024];
  const int tid = threadIdx.x, lane = tid & 63, w = tid >> 6;
  const int lr = lane & 15, lg = lane >> 4;
  const int bid = blockIdx.x;

  if (bid < 64) {
    // ========================= producer: GRU scan (v7, unchanged) =========================
    char* lds = smem;
    const int j0 = bid * 16;

    for (int c = tid; c < 6144; c += 256) {
      int chunk = c >> 6, u = c & 63;
      int g = chunk >> 5, K = chunk & 31;
      gload_lds16(whh + (size_t)(g * 1024 + j0 + (u & 15)) * 1024 + K * 32 + (u >> 4) * 8,
                  lds + (size_t)c * 16);
    }

    const int b  = w * 16 + lr;
    const int c0 = j0 + lg * 4;

    float4 bhr = *(const float4*)(bhh + c0);
    float4 bhz = *(const float4*)(bhh + 1024 + c0);
    float4 bhn = *(const float4*)(bhh + 2048 + c0);

    float4 hv = *(const float4*)(h + (size_t)b * 1024 + c0);
    f32x4 cr, cz, cn;
    {
      const float* g0 = gi + (size_t)b * 3072 + c0;
      cr = *(const f32x4*)(g0);
      cz = *(const f32x4*)(g0 + 1024);
      cn = *(const f32x4*)(g0 + 2048);
    }

    __syncthreads();

#define WAITV(n)                                               \
  asm volatile("s_waitcnt vmcnt(" #n ")" ::: "memory");        \
  __builtin_amdgcn_sched_barrier(0);
#define ISSUE8(q, ibase)                                       \
  _Pragma("unroll")                                            \
  for (int j = 0; j < 8; ++j)                                  \
    gload_b128(q[j], rowp + ((ibase) + j) * 4 + lg);
#define MFMA8(q, ibase)                                        \
  _Pragma("unroll")                                            \
  for (int j = 0; j < 8; ++j) {                                \
    _Pragma("unroll")                                          \
    for (int g = 0; g < 3; ++g) {                              \
      s16x8 wf = *reinterpret_cast<const s16x8*>(              \
          lds + (size_t)(g * 32 + (ibase) + j) * 1024 + lane * 16); \
      mfma_bf16(acc[g], wf, q[j]);                             \
    }                                                          \
  }

    for (int t = 0; t < 32; ++t) {
      const s16x8* rowp = (const s16x8*)(outs_bf + (size_t)t * 65536 + (size_t)b * 1024);

      f32x4 nr, nz, nn;
      {
        int tn = (t < 31) ? t + 1 : 31;
        const float* gn = gi + ((size_t)tn * 64 + b) * 3072 + c0;
        gload_f128(nr, gn);
        gload_f128(nz, gn + 1024);
        gload_f128(nn, gn + 2048);
      }
      s16x8 qa[8], qb[8];
      ISSUE8(qa, 0)
      ISSUE8(qb, 8)

      f32x4 acc[3];
#pragma unroll
      for (int g = 0; g < 3; ++g) acc[g] = (f32x4){0.f, 0.f, 0.f, 0.f};

      WAITV(8)
      MFMA8(qa, 0)
      ISSUE8(qa, 16)
      WAITV(8)
      MFMA8(qb, 8)
      ISSUE8(qb, 24)
      WAITV(8)
      MFMA8(qa, 16)
      WAITV(0)
      MFMA8(qb, 24)

      float hvv[4] = {hv.x, hv.y, hv.z, hv.w};
      float crr[4] = {cr[0], cr[1], cr[2], cr[3]}, czz[4] = {cz[0], cz[1], cz[2], cz[3]},
            cnn[4] = {cn[0], cn[1], cn[2], cn[3]};
      float brr[4] = {bhr.x, bhr.y, bhr.z, bhr.w}, bzz[4] = {bhz.x, bhz.y, bhz.z, bhz.w},
            bnn[4] = {bhn.x, bhn.y, bhn.z, bhn.w};
      unsigned long long pk = 0;
#pragma unroll
      for (int j = 0; j < 4; ++j) {
        float r = 1.f / (1.f + __expf(-(crr[j] + acc[0][j] + brr[j])));
        float z = 1.f / (1.f + __expf(-(czz[j] + acc[1][j] + bzz[j])));
        float n = tanhf(cnn[j] + r * (acc[2][j] + bnn[j]));
        hvv[j] = n + z * (hvv[j] - n);
        pk |= (unsigned long long)f2bf(hvv[j]) << (16 * j);
      }
      hv = (float4){hvv[0], hvv[1], hvv[2], hvv[3]};
      cr = nr; cz = nz; cn = nn;

      __hip_atomic_store(
          (unsigned long long*)(outs_bf + (size_t)(t + 1) * 65536 + (size_t)b * 1024 + c0),
          pk, __ATOMIC_RELAXED, __HIP_MEMORY_SCOPE_AGENT);

      asm volatile("s_waitcnt vmcnt(0)" ::: "memory");  // h stores acked at MALL
      __syncthreads();
      if (tid == 0)
        __hip_atomic_store(&bar[bid * 32], (unsigned)(t + 1),
                           __ATOMIC_RELAXED, __HIP_MEMORY_SCOPE_AGENT);
      if (t < 31) {
        if (tid < 64) {
          while (__hip_atomic_load(&bar[tid * 32], __ATOMIC_RELAXED,
                                   __HIP_MEMORY_SCOPE_AGENT) < (unsigned)(t + 1))
            __builtin_amdgcn_s_sleep(1);
        }
        __syncthreads();
      }
    }
#undef WAITV
#undef ISSUE8
#undef MFMA8

    *(float4*)(h + (size_t)b * 1024 + c0) = hv;

  } else {
    // ========================= consumer: logits GEMM (3-deep counted pipeline) ============
    const unsigned short* Ag = outs_bf + 65536;   // slot 1 = timestep 0
    const unsigned short* Bg = fcw;
    const int cb = bid - 64;
    const int wr = w >> 1, wc = w & 1;
    const int crow = tid >> 3, cj = tid & 7;

#define CWAIT(n)                                               \
    asm volatile("s_waitcnt vmcnt(" #n ")" ::: "memory");      \
    __builtin_amdgcn_sched_barrier(0);
#define CBAR()                                                 \
    __builtin_amdgcn_s_barrier();                              \
    __builtin_amdgcn_sched_barrier(0);
// stage one 128x64 K-step of A and B into buffer at byte base `base`
// (A at +0, B at +16384; linear LDS dest, pre-swizzled global source)
#define CSTG(base, kt)                                                                   \
    _Pragma("unroll")                                                                    \
    for (int it = 0; it < 4; ++it) {                                                     \
      int row = it * 32 + crow;                                                          \
      int sb = ((cj * 16) ^ ((row & 7) << 4)) >> 1;                                      \
      gload_lds16(Ag + (size_t)(m0 + row) * 1024 + (kt) + sb, (base) + row * 128 + cj * 16);         \
      gload_lds16(Bg + (size_t)(n0 + row) * 1024 + (kt) + sb, (base) + 16384 + row * 128 + cj * 16); \
    }
#define CCMP(base)                                                                       \
    _Pragma("unroll")                                                                    \
    for (int kk = 0; kk < 2; ++kk) {                                                     \
      s16x8 af[4], bfr[4];                                                               \
      _Pragma("unroll")                                                                  \
      for (int m = 0; m < 4; ++m) {                                                      \
        int row = wr * 64 + m * 16 + lr;                                                 \
        int off = (kk * 64 + lg * 16) ^ ((row & 7) << 4);                                \
        af[m] = *reinterpret_cast<const s16x8*>((base) + row * 128 + off);               \
      }                                                                                  \
      _Pragma("unroll")                                                                  \
      for (int n = 0; n < 4; ++n) {                                                      \
        int row = wc * 64 + n * 16 + lr;                                                 \
        int off = (kk * 64 + lg * 16) ^ ((row & 7) << 4);                                \
        bfr[n] = *reinterpret_cast<const s16x8*>((base) + 16384 + row * 128 + off);      \
      }                                                                                  \
      _Pragma("unroll")                                                                  \
      for (int m = 0; m < 4; ++m)                                                        \
        _Pragma("unroll")                                                                \
        for (int n = 0; n < 4; ++n) mfma_bf16(acc[m][n], af[m], bfr[n]);                 \
    }

    for (int tau = cb; tau < 4000; tau += 176) {
      int mt = tau / 250, nt = tau - mt * 250;
      int m0 = mt * 128, n0 = nt * 128;

      // wait until timesteps 2mt, 2mt+1 published by all 64 producers
      // (wave 0 only; slow poll to keep probe traffic off the scan's path)
      unsigned need = 2u * (unsigned)mt + 2u;
      if (w == 0) {
        while (!__all(__hip_atomic_load(&bar[lane * 32], __ATOMIC_RELAXED,
                                        __HIP_MEMORY_SCOPE_AGENT) >= need))
          __builtin_amdgcn_s_sleep(32);
      }
      CBAR()   // releases all waves once wave 0 confirms readiness

      f32x4 acc[4][4];
#pragma unroll
      for (int m = 0; m < 4; ++m)
#pragma unroll
        for (int n = 0; n < 4; ++n) acc[m][n] = (f32x4){0.f, 0.f, 0.f, 0.f};

      // prologue: stage K-steps 0,1 into buf0,buf1 (16 loads/thread in flight)
      CSTG(smem, 0)
      CSTG(smem + 32768, 64)

      // main loop: stage(ki+2) -> vmcnt(16) [stage(ki) landed] -> bar -> compute -> bar
#pragma unroll
      for (int ki = 0; ki < 16; ++ki) {
        char* cur = smem + (ki % 3) * 32768;
        if (ki + 2 < 16) {
          char* nxt = smem + ((ki + 2) % 3) * 32768;
          CSTG(nxt, (ki + 2) * 64)
        }
        if (ki < 14)       { CWAIT(16) }
        else if (ki == 14) { CWAIT(8) }
        else               { CWAIT(0) }
        CBAR()
        CCMP(cur)
        CBAR()
      }

      float bv[4];
#pragma unroll
      for (int n = 0; n < 4; ++n) bv[n] = fcb[n0 + wc * 64 + n * 16 + lr];
#pragma unroll
      for (int m = 0; m < 4; ++m)
#pragma unroll
        for (int n = 0; n < 4; ++n)
#pragma unroll
          for (int j = 0; j < 4; ++j) acc[m][n][j] += bv[n];

#pragma unroll
      for (int m = 0; m < 4; ++m) {
        int rbase = m0 + wr * 64 + m * 16 + lg * 4;
#pragma unroll
        for (int j = 0; j < 4; ++j) {
          size_t roff = (size_t)(rbase + j) * 32000;
#pragma unroll
          for (int n = 0; n < 4; ++n) {
            size_t idx = roff + n0 + wc * 64 + n * 16 + lr;
            if (OUTBF) Cb[idx] = f2bf(acc[m][n][j]);
            else       Cf[idx] = acc[m][n][j];
          }
        }
      }

      // per-tile softmax partials (sstat aliases buf0 — K-loop buffers are dead)
      float2* sstat = (float2*)smem;
#pragma unroll
      for (int m = 0; m < 4; ++m) {
#pragma unroll
        for (int j = 0; j < 4; ++j) {
          float vmax = acc[m][0][j];
#pragma unroll
          for (int n = 1; n < 4; ++n) vmax = fmaxf(vmax, acc[m][n][j]);
#pragma unroll
          for (int s = 1; s < 16; s <<= 1) vmax = fmaxf(vmax, __shfl_xor(vmax, s, 64));
          float ss = 0.f;
#pragma unroll
          for (int n = 0; n < 4; ++n) ss += __expf(acc[m][n][j] - vmax);
#pragma unroll
          for (int s = 1; s < 16; s <<= 1) ss += __shfl_xor(ss, s, 64);
          if (lr == 0) sstat[wc * 128 + wr * 64 + m * 16 + lg * 4 + j] = make_float2(vmax, ss);
        }
      }
      __syncthreads();   // full drain: vmcnt->0, so next tile's counted waits stay exact
      if (tid < 128) {
        float2 a = sstat[tid], b2 = sstat[128 + tid];
        float Mx = fmaxf(a.x, b2.x);
        float S = a.y * __expf(a.x - Mx) + b2.y * __expf(b2.x - Mx);
        stats[(size_t)(m0 + tid) * 250 + nt] = make_float2(Mx, S);
      }
      __syncthreads();   // sstat reads done before next tile's staging overwrites buf0
    }
#undef CWAIT
#undef CBAR
#undef CSTG
#undef CCMP
  }
}

// ---------------- per-row logZ from tile partials ----------------
__launch_bounds__(256)
__global__ void reduce_logz(const float2* __restrict__ stats, float* __restrict__ logZ, int nt) {
  int gid = blockIdx.x * blockDim.x + threadIdx.x;
  int row = gid >> 6, lane = gid & 63;
  const float2* s = stats + (size_t)row * nt;
  float M = -3.4e38f;
  for (int i = lane; i < nt; i += 64) M = fmaxf(M, s[i].x);
#pragma unroll
  for (int sh = 1; sh < 64; sh <<= 1) M = fmaxf(M, __shfl_xor(M, sh, 64));
  float S = 0.f;
  for (int i = lane; i < nt; i += 64) S += s[i].y * __expf(s[i].x - M);
#pragma unroll
  for (int sh = 1; sh < 64; sh <<= 1) S += __shfl_xor(S, sh, 64);
  if (lane == 0) logZ[row] = M + logf(S);
}

// ---------------- fixup (fast path): bf16 logits -> fp32 log_probs ----------------
__launch_bounds__(256)
__global__ void fixup_bf(const unsigned short* __restrict__ lbf, const float* __restrict__ logZ,
                         float* __restrict__ out) {
  const int n8 = 2048 * 32000 / 8;
  for (int i = blockIdx.x * 256 + threadIdx.x; i < n8; i += gridDim.x * 256) {
    s16x8 v = reinterpret_cast<const s16x8*>(lbf)[i];
    float z = logZ[i / 4000];
    float4 o0, o1;
    o0.x = bf2f((unsigned short)v[0]) - z; o0.y = bf2f((unsigned short)v[1]) - z;
    o0.z = bf2f((unsigned short)v[2]) - z; o0.w = bf2f((unsigned short)v[3]) - z;
    o1.x = bf2f((unsigned short)v[4]) - z; o1.y = bf2f((unsigned short)v[5]) - z;
    o1.z = bf2f((unsigned short)v[6]) - z; o1.w = bf2f((unsigned short)v[7]) - z;
    reinterpret_cast<float4*>(out)[2 * i]     = o0;
    reinterpret_cast<float4*>(out)[2 * i + 1] = o1;
  }
}

// ---------------- fixup (fallback): in-place RMW on fp32 logits ----------------
__launch_bounds__(256)
__global__ void fixup_rmw(float* __restrict__ out, const float* __restrict__ logZ) {
  const size_t total4 = 65536000u / 4u;
  for (size_t i = blockIdx.x * (size_t)blockDim.x + threadIdx.x; i < total4;
       i += (size_t)gridDim.x * blockDim.x) {
    float4 v = ((float4*)out)[i];
    int row = (int)((i * 4) / 32000);
    float z = logZ[row];
    v.x -= z; v.y -= z; v.z -= z; v.w -= z;
    ((float4*)out)[i] = v;
  }
}

// ---------------- h_last copy ----------------
__launch_bounds__(256)
__global__ void copy_h(const float* __restrict__ src, float* __restrict__ dst) {
  int i = blockIdx.x * 256 + threadIdx.x;
  ((float4*)dst)[i] = ((const float4*)src)[i];
}

extern "C" void kernel_launch(void* const* d_in, const int* in_sizes, int n_in,
                              void* d_out, int out_size, void* d_ws, size_t ws_size,
                              hipStream_t stream) {
  const int*   target = (const int*)d_in[0];
  const float* hidden = (const float*)d_in[2];
  const float* emb    = (const float*)d_in[3];
  const float* wih    = (const float*)d_in[4];
  const float* whh    = (const float*)d_in[5];
  const float* bih    = (const float*)d_in[6];
  const float* bhh    = (const float*)d_in[7];
  const float* fcw    = (const float*)d_in[8];
  const float* fcb    = (const float*)d_in[9];
  float* out = (float*)d_out;

  const int L = 32, B = 64, H = 1024, V = 32000;
  const int LB = L * B;                 // 2048
  const int NT_LOGITS = V / 128;        // 250
  const int MT = LB / 128;              // 16

  char* ws = (char*)d_ws;
  size_t off = 0;
  auto alloc = [&](size_t bytes) -> void* {
    void* p = ws + off;
    off += (bytes + 255) & ~(size_t)255;
    return p;
  };
  unsigned short* wih_bf  = (unsigned short*)alloc((size_t)3 * H * H * 2);
  unsigned short* whh_bf  = (unsigned short*)alloc((size_t)3 * H * H * 2);
  unsigned short* fcw_bf  = (unsigned short*)alloc((size_t)V * H * 2);
  unsigned short* x_bf    = (unsigned short*)alloc((size_t)LB * H * 2);
  unsigned short* outs_bf = (unsigned short*)alloc((size_t)(L + 1) * B * H * 2);
  float*          gi      = (float*)alloc((size_t)LB * 3 * H * 4);
  float*          hA      = (float*)alloc((size_t)B * H * 4);
  float2*         stats   = (float2*)alloc((size_t)LB * NT_LOGITS * 8);
  float*          logZ    = (float*)alloc((size_t)LB * 4);
  unsigned*       bar     = (unsigned*)alloc(64 * 128);   // 64 flags, 128B apart
  size_t lbf_bytes = (size_t)LB * V * 2;
  unsigned short* lbf = (unsigned short*)(ws + off);
  bool big = (off + lbf_bytes) <= ws_size;
  (void)in_sizes; (void)n_in; (void)out_size;

  // weights -> bf16
  cvt_bf16<<<2048, 256, 0, stream>>>(wih, wih_bf, 3 * H * H / 4);
  cvt_bf16<<<2048, 256, 0, stream>>>(whh, whh_bf, 3 * H * H / 4);
  cvt_bf16<<<2048, 256, 0, stream>>>(fcw, fcw_bf, V * H / 4);

  // h0
  init_h<<<64, 256, 0, stream>>>(hidden, hA, outs_bf);

  // x = relu(emb[tokens]) -> bf16
  embed_relu<<<LB, 256, 0, stream>>>(target, emb, x_bf);

  // gi = x @ w_ih^T + b_ih   (M=2048, N=3072, K=1024)
  gemm_bt<false, false><<<(3 * H / 128) * MT, 256, 0, stream>>>(
      x_bf, wih_bf, bih, gi, nullptr, nullptr, 3 * H, H, MT, 3 * H / 128);

  // fused persistent scan + logits GEMM (flags zeroed each call -> deterministic)
  hipMemsetAsync(bar, 0, 64 * 128, stream);
  if (big) {
    scan_fused<true><<<240, 256, 0, stream>>>(
        whh_bf, gi, bhh, hA, outs_bf, bar, fcw_bf, fcb, nullptr, lbf, stats);
    reduce_logz<<<LB * 64 / 256, 256, 0, stream>>>(stats, logZ, NT_LOGITS);
    fixup_bf<<<2048, 256, 0, stream>>>(lbf, logZ, out);
  } else {
    scan_fused<false><<<240, 256, 0, stream>>>(
        whh_bf, gi, bhh, hA, outs_bf, bar, fcw_bf, fcb, out, nullptr, stats);
    reduce_logz<<<LB * 64 / 256, 256, 0, stream>>>(stats, logZ, NT_LOGITS);
    fixup_rmw<<<2048, 256, 0, stream>>>(out, logZ);
  }

  // h_last
  copy_h<<<64, 256, 0, stream>>>(hA, out + (size_t)LB * V);
}